// Round 1
// baseline (316.783 us; speedup 1.0000x reference)
//
#include <hip/hip_runtime.h>
#include <hip/hip_bf16.h>
#include <stdint.h>

#define LSEQ 200
#define DDIM 128

typedef __attribute__((ext_vector_type(8))) __bf16 bf16x8;
typedef __attribute__((ext_vector_type(4))) float f32x4;

__device__ __forceinline__ float fast_exp(float x) {
  return __builtin_amdgcn_exp2f(x * 1.4426950408889634f);
}
__device__ __forceinline__ float fast_sigmoid(float x) {
  return __builtin_amdgcn_rcpf(1.0f + fast_exp(-x));
}
__device__ __forceinline__ float fast_tanh(float x) {
  float ax = __builtin_fabsf(x);
  float t = __builtin_amdgcn_exp2f(ax * -2.885390081777927f);  // exp(-2|x|)
  float r = (1.0f - t) * __builtin_amdgcn_rcpf(1.0f + t);
  return x < 0.0f ? -r : r;
}

__device__ __forceinline__ f32x4 mfma16(bf16x8 a, bf16x8 b, f32x4 c) {
  return __builtin_amdgcn_mfma_f32_16x16x32_bf16(a, b, c, 0, 0, 0);
}

// Kernel 1: scores + masked softmax -> attn_T[t][b] (0 where masked),
// and h_states fp32 -> bf16 packed in MFMA A-fragment order:
// xp frag (t, b16, kt): lane l, elem j = x[b16*16 + (l&15)][t][kt*32 + (l>>4)*8 + j]
__global__ __launch_bounds__(512) void k_scores_pack(
    const float* __restrict__ h_states, const float* __restrict__ target,
    const int* __restrict__ mask, uint4* __restrict__ xp,
    float* __restrict__ attnT, int B) {
  __shared__ float s_sc[4][16][LSEQ];   // per-kt partial dots
  __shared__ float s_tgt[16][DDIM];
  const int b16 = blockIdx.x;
  const int bb = b16 * 16;
  const int tid = threadIdx.x;
  for (int i = tid; i < 16 * DDIM; i += 512)
    s_tgt[i >> 7][i & 127] = target[(size_t)(bb + (i >> 7)) * DDIM + (i & 127)];
  __syncthreads();

  const int lane = tid & 63;
  const int kt = (tid >> 6) & 3;
  const int tp = tid >> 8;           // t parity handled by this half of block
  const int row = lane & 15;
  const int hi = lane >> 4;
  const int kbase = kt * 32 + hi * 8;
  const int B16 = B >> 4;
  const float* src = h_states + ((size_t)(bb + row) * LSEQ) * DDIM + kbase;
  const float* tg = &s_tgt[row][kbase];

  for (int t = tp; t < LSEQ; t += 2) {
    float4 a = *(const float4*)(src + (size_t)t * DDIM);
    float4 b = *(const float4*)(src + (size_t)t * DDIM + 4);
    float dv = (a.x * tg[0] + a.y * tg[1] + a.z * tg[2] + a.w * tg[3]) +
               (b.x * tg[4] + b.y * tg[5] + b.z * tg[6] + b.w * tg[7]);
    dv += __shfl_xor(dv, 16);
    dv += __shfl_xor(dv, 32);
    if (hi == 0) s_sc[kt][row][t] = dv;
    union { __bf16 h[8]; uint4 v; } pk;
    pk.h[0] = (__bf16)a.x; pk.h[1] = (__bf16)a.y; pk.h[2] = (__bf16)a.z; pk.h[3] = (__bf16)a.w;
    pk.h[4] = (__bf16)b.x; pk.h[5] = (__bf16)b.y; pk.h[6] = (__bf16)b.z; pk.h[7] = (__bf16)b.w;
    xp[(((size_t)t * B16 + b16) * 4 + kt) * 64 + lane] = pk.v;
  }
  __syncthreads();

  if (tid < 256) {
    const int r2 = tid >> 4;
    const int j = tid & 15;
    const int* mrow = mask + (size_t)(bb + r2) * LSEQ;
    float mx = -3.0e38f;
    for (int t = j; t < LSEQ; t += 16) {
      float s = (s_sc[0][r2][t] + s_sc[1][r2][t]) + (s_sc[2][r2][t] + s_sc[3][r2][t]);
      s *= 0.088388347648318447f;  // 1/sqrt(128)
      s = (mrow[t] != 0) ? s : -3.0e38f;
      s_sc[0][r2][t] = s;
      mx = fmaxf(mx, s);
    }
    mx = fmaxf(mx, __shfl_xor(mx, 1));
    mx = fmaxf(mx, __shfl_xor(mx, 2));
    mx = fmaxf(mx, __shfl_xor(mx, 4));
    mx = fmaxf(mx, __shfl_xor(mx, 8));
    float se = 0.0f;
    for (int t = j; t < LSEQ; t += 16) {
      float e = fast_exp(s_sc[0][r2][t] - mx);
      s_sc[1][r2][t] = e;
      se += e;
    }
    se += __shfl_xor(se, 1);
    se += __shfl_xor(se, 2);
    se += __shfl_xor(se, 4);
    se += __shfl_xor(se, 8);
    float rs = __builtin_amdgcn_rcpf(se);
    for (int t = j; t < LSEQ; t += 16)
      attnT[(size_t)t * B + bb + r2] = (mrow[t] != 0) ? s_sc[1][r2][t] * rs : 0.0f;
  }
}

// Kernel 2: the recurrence. 1 block = 16 batch rows, 8 waves x 16 output cols.
// Weights live in VGPRs as bf16 B-fragments for all 200 steps. h state fp32 in
// registers (D-layout); bf16 copies for MFMA A-operands round-trip through LDS.
__global__ __launch_bounds__(512, 2) void k_recur(
    const uint4* __restrict__ xp, const float* __restrict__ attnT,
    const float* __restrict__ Wr, const float* __restrict__ br,
    const float* __restrict__ Wu, const float* __restrict__ bu,
    const float* __restrict__ Wh, const float* __restrict__ bh,
    float* __restrict__ out, int B) {
  __shared__ __bf16 s_rh[16][136];  // pad 128->136: conflict-free ds_read_b128
  __shared__ __bf16 s_hb[16][136];
  __shared__ float s_att[LSEQ][16];
  const int tid = threadIdx.x;
  const int lane = tid & 63;
  const int wv = tid >> 6;
  const int b16 = blockIdx.x;
  const int bb = b16 * 16;
  const int g = lane >> 4;       // D-layout row group
  const int rA = lane & 15;      // A-fragment row
  const int col = wv * 16 + rA;  // this lane's output column
  const int B16 = B >> 4;

  // Load weight B-fragments (bf16). wX[kt] covers W rows [kt*32, kt*32+32):
  // kt 0..3 = x-part, kt 4..7 = h-part.
  bf16x8 wr[8], wu[8], wh[8];
#pragma unroll
  for (int kt = 0; kt < 8; ++kt) {
    bf16x8 tr, tu, th;
    int krow = kt * 32 + g * 8;
#pragma unroll
    for (int j = 0; j < 8; ++j) {
      tr[j] = (__bf16)Wr[(size_t)(krow + j) * DDIM + col];
      tu[j] = (__bf16)Wu[(size_t)(krow + j) * DDIM + col];
      th[j] = (__bf16)Wh[(size_t)(krow + j) * DDIM + col];
    }
    wr[kt] = tr; wu[kt] = tu; wh[kt] = th;
  }
  const float biasr = br[col], biasu = bu[col], biash = bh[col];

  for (int i = tid; i < LSEQ * 16; i += 512)
    s_att[i >> 4][i & 15] = attnT[(size_t)(i >> 4) * B + bb + (i & 15)];
  for (int i = tid; i < 16 * 136; i += 512)
    (&s_hb[0][0])[i] = (__bf16)0.0f;
  __syncthreads();

  float hD[4] = {0.f, 0.f, 0.f, 0.f};
  uint4 xc[4], xn[4];
  {
    size_t base = (size_t)b16 * 4;
#pragma unroll
    for (int kt = 0; kt < 4; ++kt) xc[kt] = xp[(base + kt) * 64 + lane];
  }

  for (int t = 0; t < LSEQ; ++t) {
    // prefetch next step's x fragments (stays in flight across raw barriers)
    if (t + 1 < LSEQ) {
      size_t base = ((size_t)(t + 1) * B16 + b16) * 4;
#pragma unroll
      for (int kt = 0; kt < 4; ++kt) xn[kt] = xp[(base + kt) * 64 + lane];
    }
    // Phase A: r, u gates
    bf16x8 hf[4];
#pragma unroll
    for (int kt = 0; kt < 4; ++kt)
      hf[kt] = *(const bf16x8*)&s_hb[rA][kt * 32 + g * 8];
    f32x4 accr = {biasr, biasr, biasr, biasr};
    f32x4 accu = {biasu, biasu, biasu, biasu};
#pragma unroll
    for (int kt = 0; kt < 4; ++kt) {
      bf16x8 a = __builtin_bit_cast(bf16x8, xc[kt]);
      accr = mfma16(a, wr[kt], accr);
      accu = mfma16(a, wu[kt], accu);
    }
#pragma unroll
    for (int kt = 0; kt < 4; ++kt) {
      accr = mfma16(hf[kt], wr[4 + kt], accr);
      accu = mfma16(hf[kt], wu[4 + kt], accu);
    }
    float rr[4], uu[4];
#pragma unroll
    for (int j = 0; j < 4; ++j) {
      rr[j] = fast_sigmoid(accr[j]);
      uu[j] = fast_sigmoid(accu[j]);
      s_rh[g * 4 + j][col] = (__bf16)(rr[j] * hD[j]);
    }
    __builtin_amdgcn_sched_barrier(0);
    asm volatile("s_waitcnt lgkmcnt(0)" ::: "memory");
    __builtin_amdgcn_s_barrier();
    __builtin_amdgcn_sched_barrier(0);
    // Phase B: h_tilde and state update
    bf16x8 rf[4];
#pragma unroll
    for (int kt = 0; kt < 4; ++kt)
      rf[kt] = *(const bf16x8*)&s_rh[rA][kt * 32 + g * 8];
    f32x4 acch = {biash, biash, biash, biash};
#pragma unroll
    for (int kt = 0; kt < 4; ++kt) {
      bf16x8 a = __builtin_bit_cast(bf16x8, xc[kt]);
      acch = mfma16(a, wh[kt], acch);
      acch = mfma16(rf[kt], wh[4 + kt], acch);
    }
#pragma unroll
    for (int j = 0; j < 4; ++j) {
      float ht = fast_tanh(acch[j]);
      float up = s_att[t][g * 4 + j] * uu[j];  // attn==0 where masked -> h unchanged
      hD[j] += up * (ht - hD[j]);
      s_hb[g * 4 + j][col] = (__bf16)hD[j];
    }
    __builtin_amdgcn_sched_barrier(0);
    asm volatile("s_waitcnt lgkmcnt(0)" ::: "memory");
    __builtin_amdgcn_s_barrier();
    __builtin_amdgcn_sched_barrier(0);
#pragma unroll
    for (int kt = 0; kt < 4; ++kt) xc[kt] = xn[kt];
  }
#pragma unroll
  for (int j = 0; j < 4; ++j)
    out[(size_t)(bb + g * 4 + j) * DDIM + col] = hD[j];
}

extern "C" void kernel_launch(void* const* d_in, const int* in_sizes, int n_in,
                              void* d_out, int out_size, void* d_ws, size_t ws_size,
                              hipStream_t stream) {
  const float* h_states = (const float*)d_in[0];
  const float* target   = (const float*)d_in[1];
  const int*   mask     = (const int*)d_in[2];
  const float* Wr = (const float*)d_in[3];
  const float* br = (const float*)d_in[4];
  const float* Wu = (const float*)d_in[5];
  const float* bu = (const float*)d_in[6];
  const float* Wh = (const float*)d_in[7];
  const float* bh = (const float*)d_in[8];

  const int B = in_sizes[0] / (LSEQ * DDIM);  // 4096
  // workspace layout: [xp: B*L*128 bf16][attnT: L*B fp32]
  uint4* xp = (uint4*)d_ws;
  float* attnT = (float*)((char*)d_ws + (size_t)B * LSEQ * DDIM * 2);

  k_scores_pack<<<B / 16, 512, 0, stream>>>(h_states, target, mask, xp, attnT, B);
  k_recur<<<B / 16, 512, 0, stream>>>(xp, attnT, Wr, br, Wu, bu, Wh, bh,
                                      (float*)d_out, B);
}